// Round 1
// baseline (1421.690 us; speedup 1.0000x reference)
//
#include <hip/hip_runtime.h>
#include <stdint.h>

// Problem constants
#define B 16
#define C 2048
#define T 8192
#define K 64
#define CCHUNKS 4
#define CPER (C / CCHUNKS)   // 512

// ---------------------------------------------------------------------------
// Stage 1: partial attention scores.
// part[cc][b][t] = sum_{c in chunk cc} x[b,c,t] * w[c]
// Grid: (T/1024, CCHUNKS, B) = (8,4,16) = 512 blocks, 256 threads.
// Each thread owns 4 consecutive t (one float4), loops 512 c's.
// Memory-bound streaming read of all of x (512 MiB).
// ---------------------------------------------------------------------------
__global__ void __launch_bounds__(256)
attn_partial_kernel(const float* __restrict__ x,
                    const float* __restrict__ w,
                    float* __restrict__ part)
{
    const int tt = blockIdx.x;   // t-tile 0..7
    const int cc = blockIdx.y;   // c-chunk 0..3
    const int b  = blockIdx.z;   // batch  0..15
    const int t  = tt * 1024 + threadIdx.x * 4;

    const float4* xp = reinterpret_cast<const float4*>(
        x + ((size_t)b * C + (size_t)cc * CPER) * T + t);
    const float* wp = w + cc * CPER;

    float4 acc = make_float4(0.f, 0.f, 0.f, 0.f);
#pragma unroll 8
    for (int c = 0; c < CPER; ++c) {
        const float  wv = wp[c];                   // wave-uniform -> s_load, sL1-hit
        const float4 xv = xp[(size_t)c * (T / 4)]; // coalesced 16B/lane
        acc.x += xv.x * wv;
        acc.y += xv.y * wv;
        acc.z += xv.z * wv;
        acc.w += xv.w * wv;
    }

    float4* pp = reinterpret_cast<float4*>(
        part + ((size_t)cc * B + b) * T + t);
    *pp = acc;
}

// ---------------------------------------------------------------------------
// Stage 2: exact top-64 per batch with jax lax.top_k semantics
// (sorted descending; ties -> lower index first).
// One block per batch, 1024 threads; each thread holds 8 candidates in
// registers as monotone uint64 keys: (ordered_float << 32) | ~t.
// 64 iterations of block-wide argmax; winner excluded by zeroing its key.
// ---------------------------------------------------------------------------
__global__ void __launch_bounds__(1024)
topk_kernel(const float* __restrict__ part,
            const float* __restrict__ bptr,
            float* __restrict__ out_idx_f,   // d_out chunk 1: indices as float
            int*   __restrict__ ws_idx,      // for gather kernel
            float* __restrict__ ws_scale)    // v + (1 - v), faithful to ref
{
    const int b    = blockIdx.x;
    const int tid  = threadIdx.x;
    const int lane = tid & 63;
    const int wid  = tid >> 6;
    const float bias = bptr[0];
    const int tbase = tid * 8;

    float s[8];
#pragma unroll
    for (int j = 0; j < 8; ++j) s[j] = 0.f;

#pragma unroll
    for (int ch = 0; ch < CCHUNKS; ++ch) {
        const float4* p = reinterpret_cast<const float4*>(
            part + ((size_t)ch * B + b) * T + tbase);
        const float4 a = p[0];
        const float4 c4 = p[1];
        s[0] += a.x;  s[1] += a.y;  s[2] += a.z;  s[3] += a.w;
        s[4] += c4.x; s[5] += c4.y; s[6] += c4.z; s[7] += c4.w;
    }

    unsigned long long key[8];
#pragma unroll
    for (int j = 0; j < 8; ++j) {
        const float v = s[j] + bias;
        const unsigned int u   = __float_as_uint(v);
        const unsigned int ord = (u & 0x80000000u) ? ~u : (u | 0x80000000u);
        key[j] = ((unsigned long long)ord << 32) |
                 (unsigned int)(~(unsigned int)(tbase + j));
    }

    __shared__ unsigned long long wmax[16];
    __shared__ unsigned long long winner;

    for (int k = 0; k < K; ++k) {
        unsigned long long m = key[0];
#pragma unroll
        for (int j = 1; j < 8; ++j) m = (key[j] > m) ? key[j] : m;

#pragma unroll
        for (int off = 32; off >= 1; off >>= 1) {
            const unsigned long long o = __shfl_down(m, off, 64);
            m = (o > m) ? o : m;
        }
        if (lane == 0) wmax[wid] = m;
        __syncthreads();

        if (tid == 0) {
            unsigned long long mm = wmax[0];
            for (int i = 1; i < 16; ++i) mm = (wmax[i] > mm) ? wmax[i] : mm;
            winner = mm;
            const unsigned int low = (unsigned int)mm;
            const int tsel = (int)(~low);
            const unsigned int ord = (unsigned int)(mm >> 32);
            const unsigned int u =
                (ord & 0x80000000u) ? (ord ^ 0x80000000u) : ~ord;
            const float v = __uint_as_float(u);
            out_idx_f[b * K + k] = (float)tsel;
            ws_idx[b * K + k]    = tsel;
            ws_scale[b * K + k]  = v + (1.0f - v);  // == ref's values+(1-values)
        }
        __syncthreads();

        const unsigned long long wn = winner;
#pragma unroll
        for (int j = 0; j < 8; ++j)
            if (key[j] == wn) key[j] = 0ull;
        // next iteration's wmax write happens only after all threads passed
        // the sync above and read `winner` -> no race
    }
}

// ---------------------------------------------------------------------------
// Stage 3: gather latents. out[b,k,c] = x[b,c,idx[b,k]] * scale[b,k]
// Grid (K, B) = 1024 blocks, 256 threads; thread owns 8 consecutive c.
// Reads are strided (32 KiB apart) -> structural 64B-line overfetch;
// writes are fully coalesced float4.
// ---------------------------------------------------------------------------
__global__ void __launch_bounds__(256)
gather_kernel(const float* __restrict__ x,
              const int*   __restrict__ ws_idx,
              const float* __restrict__ ws_scale,
              float* __restrict__ out)
{
    const int k = blockIdx.x;
    const int b = blockIdx.y;
    const int t  = ws_idx[b * K + k];    // wave-uniform scalar load
    const float sc = ws_scale[b * K + k];
    const int c0 = threadIdx.x * 8;

    const float* xp = x + ((size_t)b * C + c0) * T + t;
    float v[8];
#pragma unroll
    for (int j = 0; j < 8; ++j) v[j] = xp[(size_t)j * T];

    const float4 o0 = make_float4(v[0] * sc, v[1] * sc, v[2] * sc, v[3] * sc);
    const float4 o1 = make_float4(v[4] * sc, v[5] * sc, v[6] * sc, v[7] * sc);
    float4* op = reinterpret_cast<float4*>(
        out + ((size_t)(b * K + k)) * C + c0);
    op[0] = o0;
    op[1] = o1;
}

// ---------------------------------------------------------------------------
extern "C" void kernel_launch(void* const* d_in, const int* in_sizes, int n_in,
                              void* d_out, int out_size, void* d_ws, size_t ws_size,
                              hipStream_t stream)
{
    const float* x  = (const float*)d_in[0];   // [16,2048,8192]
    const float* w  = (const float*)d_in[1];   // [2048]
    const float* bb = (const float*)d_in[2];   // [1]

    float* out       = (float*)d_out;               // latents [16,64,2048]
    float* out_idx_f = out + (size_t)B * K * C;     // indices [16,64] as f32

    // ws layout: partial sums (2 MiB) | ws_idx (4 KiB) | ws_scale (4 KiB)
    float* part     = (float*)d_ws;
    int*   ws_idx   = (int*)((char*)d_ws + (size_t)CCHUNKS * B * T * sizeof(float));
    float* ws_scale = (float*)(ws_idx + B * K);

    hipLaunchKernelGGL(attn_partial_kernel,
                       dim3(T / 1024, CCHUNKS, B), dim3(256), 0, stream,
                       x, w, part);
    hipLaunchKernelGGL(topk_kernel,
                       dim3(B), dim3(1024), 0, stream,
                       part, bb, out_idx_f, ws_idx, ws_scale);
    hipLaunchKernelGGL(gather_kernel,
                       dim3(K, B), dim3(256), 0, stream,
                       x, ws_idx, ws_scale, out);
}